// Round 3
// baseline (447.360 us; speedup 1.0000x reference)
//
#include <hip/hip_runtime.h>
#include <math.h>

namespace {
constexpr int kB    = 32;
constexpr int kMel  = 128;
constexpr int kT    = 8192;
constexpr int kKeys = 88;
constexpr int kTop  = 15;   // top[13] = 14th largest, top[14] = 15th largest
}

__device__ __forceinline__ void top_insert(float (&top)[kTop], float v) {
#pragma unroll
  for (int j = 0; j < kTop; ++j) {
    const float hi = fmaxf(top[j], v);
    v = fminf(top[j], v);
    top[j] = hi;
  }
}

// Log-domain sum for key bin m (wave-uniform m). Same inlined expression in
// both phases -> bit-identical results, so rank decisions are consistent.
__device__ __forceinline__ float logsum(const float* __restrict__ melb, int m) {
  const int r1 = (m < 64) ? 2 * m : m;   // dummy -> same row (in-bounds, L1-hot)
  const int r2 = (m < 43) ? 3 * m : m;
  const float w1 = (m < 64) ? 1.0f : 0.0f;
  const float w2 = (m < 43) ? 1.0f : 0.0f;
  const float v0 = melb[(size_t)m * kT];
  const float v1 = melb[(size_t)r1 * kT];
  const float v2 = melb[(size_t)r2 * kT];
  return v0 + w1 * v1 + w2 * v2;
}

// Product-space value with correctly-rounded fp32 exp (np-compatible center).
__device__ __forceinline__ float prodval(const float* __restrict__ melb, int m) {
  float v = (float)::exp((double)melb[(size_t)m * kT]);
  if (m < 64) v *= (float)::exp((double)melb[(size_t)(2 * m) * kT]);
  if (m < 43) v *= (float)::exp((double)melb[(size_t)(3 * m) * kT]);
  return v;
}

__global__ __launch_bounds__(256, 4) void key_probs_kernel(
    const float* __restrict__ mel, const int* __restrict__ key_bins,
    float* __restrict__ out) {
  __shared__ int sbins[kKeys];
  const int tid = threadIdx.x;
  if (tid < kKeys) sbins[tid] = key_bins[tid];
  __syncthreads();

  const int t = blockIdx.x * 256 + tid;
  const int b = blockIdx.y;
  const float* melb = mel + (size_t)b * kMel * kT + t;

  // ---- phase A/B: streaming top-15 selection on log-domain sums ------------
  // Only top[15] stays live (no s[88] array -> no scratch spill).
  float top[kTop];
#pragma unroll
  for (int j = 0; j < kTop; ++j) top[j] = -1e30f;  // sums can be negative
#pragma unroll
  for (int k = 0; k < kKeys; ++k) {
    const int m = __builtin_amdgcn_readfirstlane(sbins[k]);
    top_insert(top, logsum(melb, m));
  }

  float r74 = top[13];
  // Only the rank-14/15 boundary gap matters: swaps internal to the top-14
  // set (or entirely below it) cannot change the >=thresh mask. Sum-space
  // abs gap < ~2.5e-6 is where product-space fp rounding could flip it.
  const bool amb = (top[13] - top[14]) < 1e-5f;

  if (amb) {  // rare: recompute this lane's threshold in product space
    float tp[kTop];
#pragma unroll
    for (int j = 0; j < kTop; ++j) tp[j] = 0.0f;  // products are positive
#pragma unroll
    for (int k = 0; k < kKeys; ++k) {
      const int m = __builtin_amdgcn_readfirstlane(sbins[k]);
      top_insert(tp, prodval(melb, m));
    }
    r74 = tp[13];  // product-space threshold for amb lanes
  }

  // ---- phase C: recompute (L1-hot) + classify + write both outputs ---------
  float* o0 = out + (size_t)b * kKeys * kT + t;
  float* o1 = o0 + (size_t)kB * kKeys * kT;
#pragma unroll
  for (int k = 0; k < kKeys; ++k) {
    const int m = __builtin_amdgcn_readfirstlane(sbins[k]);
    float val = logsum(melb, m);           // sum-space for non-amb lanes
    if (amb) val = prodval(melb, m);       // product-space for amb lanes (rare)
    const float r = (val >= r74) ? 1.0f : 0.0f;
    o0[(size_t)k * kT] = r;
    o1[(size_t)k * kT] = r;
  }
}

extern "C" void kernel_launch(void* const* d_in, const int* in_sizes, int n_in,
                              void* d_out, int out_size, void* d_ws, size_t ws_size,
                              hipStream_t stream) {
  const float* mel = (const float*)d_in[0];
  const int* key_bins = (const int*)d_in[1];
  float* out = (float*)d_out;
  dim3 grid(kT / 256, kB);
  key_probs_kernel<<<grid, dim3(256), 0, stream>>>(mel, key_bins, out);
}